// Round 5
// baseline (648.731 us; speedup 1.0000x reference)
//
#include <hip/hip_runtime.h>

// Upsample 2x via upfirdn2d([1,3,3,1], factor 2).
//   x:   (8, 64, 256, 256) fp32
//   out: (8, 64, 511, 511) fp32
//
// Separable form (verified rounds 1-3): for output col o, q=(o>>1)+(o&1),
//   H(r,o) = wA*x[r][q-1] + wB*x[r][q],  (wA,wB) = o odd ? (k2,k0)*inv
//                                                        : (k3,k1)*inv
//   out[2r-1][o] = k2i*H(r-1,o) + k0i*H(r,o)   (absent at r==0)
//   out[2r  ][o] = k3i*H(r-1,o) + k1i*H(r,o)
//
// Round 4 (resubmit; round-4 bench was an infra failure, kernel re-audited):
// wave-autonomous, zero-barrier pipeline.
//  - One wave spans a full input row: lane l float4-loads cols 4l..4l+3
//    (1 dwordx4 per row vs 4 scalar dwords/lane before), boundary cols via
//    __shfl_up/__shfl_down.
//  - Each wave owns 8 contiguous input rows + a private LDS slice; computes
//    out rows (2r-1, 2r), stages them, and flushes with the round-3 flat
//    aligned-float4 flush (per wave, stride 64).  No __syncthreads at all:
//    no lockstep phases, flush overlaps the prefetched next-row load.
//  - Per-wave out-row coverage [2rs-1, 2rs+15) tiles the image seamlessly.

#define IN_H 256
#define IN_W 256
#define OUT_H 511
#define OUT_W 511
#define N_BC (8 * 64)
#define STRIP 32                 // input rows per block (4 waves x 8)
#define STRIPS (IN_H / STRIP)    // 8 blocks per image
#define RPW (STRIP / 4)          // 8 rows per wave
#define LDSW 1028                // dwords per wave slice (3 pad + 1022 + spill)

__global__ __launch_bounds__(256) void Upsample_64948495450678_kernel(
    const float* __restrict__ x,
    const float* __restrict__ k1d,
    float* __restrict__ out)
{
    __shared__ __align__(16) float lds[4 * LDSW];

    const int t  = threadIdx.x;
    const int l  = t & 63;                  // lane in wave
    const int w  = t >> 6;                  // wave in block
    const int bc = blockIdx.x >> 3;         // / STRIPS
    const int rs = (blockIdx.x & (STRIPS - 1)) * STRIP + w * RPW;

    float* __restrict__ L = lds + w * LDSW; // private slice

    // Uniform tap weights from the actual kernel input.
    const float k0 = k1d[0], k1 = k1d[1], k2 = k1d[2], k3 = k1d[3];
    const float inv = 2.0f / (k0 + k1 + k2 + k3);
    const float k0i = k0*inv, k1i = k1*inv, k2i = k2*inv, k3i = k3*inv;

    const float* __restrict__ xim = x + (size_t)bc * (IN_H * IN_W);

    // Horizontal filter of one input row (lane l holds cols 4l..4l+3).
    // H[j] is output col 8l+j.  Lane 63's H[7] (col 511) is never stored.
    auto hrow = [&](const float4 v, float H[8]) {
        const float um  = __shfl_up(v.w, 1);
        const float xm1 = l ? um : 0.0f;            // col -1 zero pad
        const float xp4 = __shfl_down(v.x, 1);      // col 4l+4
        H[0] = k3i*xm1 + k1i*v.x;
        H[1] = k2i*v.x + k0i*v.y;
        H[2] = k3i*v.x + k1i*v.y;
        H[3] = k2i*v.y + k0i*v.z;
        H[4] = k3i*v.y + k1i*v.z;
        H[5] = k2i*v.z + k0i*v.w;
        H[6] = k3i*v.z + k1i*v.w;
        H[7] = k2i*v.w + k0i*xp4;
    };

    // Carried H of row rs-1 (zero pad at image top).
    float Hp[8];
    if (rs == 0) {
        #pragma unroll
        for (int j = 0; j < 8; ++j) Hp[j] = 0.0f;
    } else {
        const float4 vh = *(const float4*)(xim + (size_t)(rs - 1) * IN_W + 4 * l);
        hrow(vh, Hp);
    }

    float4 xc = *(const float4*)(xim + (size_t)rs * IN_W + 4 * l);

    const size_t img_b = (size_t)bc * ((size_t)OUT_H * OUT_W * 4);
    char* __restrict__ outb = (char*)out;

    for (int i = 0; i < RPW; ++i) {
        const int r = rs + i;

        // Prefetch next row before staging/flush (hides HBM latency).
        float4 xn = xc;
        if (i < RPW - 1)
            xn = *(const float4*)(xim + (size_t)(r + 1) * IN_W + 4 * l);

        float H[8];
        hrow(xc, H);

        const int row_start = r ? (2 * r - 1) : 0;
        const int nrows     = r ? 2 : 1;
        const size_t S      = img_b + (size_t)row_start * (OUT_W * 4);
        const int pd        = (int)(S & 15) >> 2;   // LDS pad dwords
        const int eoff      = r ? OUT_W : 0;        // even-row offset in slice

        // Stage out rows into the wave's LDS slice (range-dword u -> L[pd+u]).
        if (r) {
            #pragma unroll
            for (int j = 0; j < 8; ++j) {
                // lane63 j==7 is col 511 (doesn't exist) and would alias the
                // even row's col-0 slot -> predicate it out.
                if (j < 7 || l < 63)
                    L[pd + 8 * l + j] = k2i * Hp[j] + k0i * H[j];
            }
        }
        #pragma unroll
        for (int j = 0; j < 8; ++j)          // lane63 j==7 lands in pad: harmless
            L[pd + eoff + 8 * l + j] = k3i * Hp[j] + k1i * H[j];

        // Flat aligned-float4 flush of this wave's [S, S + nrows*2044) bytes.
        {
            const int nb     = nrows * (OUT_W * 4);
            const int headB  = (16 - (int)(S & 15)) & 15;
            const int nvec   = (nb - headB) >> 4;
            const int tailB  = (nb - headB) & 15;
            const int basedw = pd + (headB >> 2);   // 16B-aligned LDS base
            char* gp = outb + S;

            if (l < (headB >> 2))
                *(float*)(gp + 4 * l) = L[pd + l];

            for (int v = l; v < nvec; v += 64) {
                const float4 q = *(const float4*)(L + basedw + 4 * v);
                *(float4*)(gp + headB + 16 * v) = q;
            }

            if (l < (tailB >> 2))
                *(float*)(gp + headB + 16 * nvec + 4 * l) =
                    L[basedw + 4 * nvec + l];
        }

        #pragma unroll
        for (int j = 0; j < 8; ++j) Hp[j] = H[j];
        xc = xn;
    }
}

extern "C" void kernel_launch(void* const* d_in, const int* in_sizes, int n_in,
                              void* d_out, int out_size, void* d_ws, size_t ws_size,
                              hipStream_t stream) {
    const float* x   = (const float*)d_in[0];
    const float* k1d = (const float*)d_in[1];
    float* out = (float*)d_out;

    dim3 block(256, 1, 1);
    dim3 grid(N_BC * STRIPS, 1, 1);   // 4096 blocks
    Upsample_64948495450678_kernel<<<grid, block, 0, stream>>>(x, k1d, out);
}